// Round 2
// baseline (503.657 us; speedup 1.0000x reference)
//
#include <hip/hip_runtime.h>

typedef unsigned int u32;

#define N_NODES  100000
#define N_EDGES  1600000
#define N_GRAPHS 128

// ---- degree over dst (self-loop +1 added in k_dinv) ----
__global__ __launch_bounds__(256) void k_deg(const int* __restrict__ dst, int* __restrict__ deg) {
    int e = blockIdx.x * 256 + threadIdx.x;
    if (e < N_EDGES) atomicAdd(&deg[dst[e]], 1);
}

// ---- nodes per graph ----
__global__ __launch_bounds__(256) void k_cnt(const int* __restrict__ batch, int* __restrict__ cntg) {
    int n = blockIdx.x * 256 + threadIdx.x;
    if (n < N_NODES) atomicAdd(&cntg[batch[n]], 1);
}

__global__ __launch_bounds__(256) void k_dinv(const int* __restrict__ deg, float* __restrict__ dinv) {
    int n = blockIdx.x * 256 + threadIdx.x;
    if (n < N_NODES) dinv[n] = rsqrtf((float)(deg[n] + 1));
}

// ---- t1 = x @ W1  [100000,128]x[128,16]; also p1 = dinv^2 * t1 (self-loop term) ----
__global__ __launch_bounds__(256) void k_gemm1(const float* __restrict__ x, const float* __restrict__ W1,
                                               const float* __restrict__ dinv,
                                               float* __restrict__ t1, float* __restrict__ p1) {
    __shared__ float w[128 * 16];      // 8 KB
    __shared__ float xs[16][132];      // padded rows, 16-row tile
    int t = threadIdx.x;
    {   // W1: 2048 floats, 256 threads x 8
        const float4* wv = (const float4*)W1;
        float4 a = wv[t * 2], b = wv[t * 2 + 1];
        ((float4*)w)[t * 2] = a;
        ((float4*)w)[t * 2 + 1] = b;
    }
    int base = blockIdx.x * 16;        // 6250 blocks * 16 rows = 100000 exactly
    {   // x tile: 16 rows x 128 = 2048 floats, coalesced float4
        const float4* xv = (const float4*)(x + (size_t)base * 128);
        #pragma unroll
        for (int q = 0; q < 2; ++q) {
            int i4 = t * 2 + q;            // float4 index within tile
            float4 v = xv[i4];
            int idx = i4 * 4;              // element index
            *((float4*)&xs[idx >> 7][idx & 127]) = v;
        }
    }
    __syncthreads();
    int nl = t >> 4, j = t & 15;
    int n = base + nl;
    const float4* xr = (const float4*)&xs[nl][0];
    float acc = 0.f;
    #pragma unroll
    for (int k4 = 0; k4 < 32; ++k4) {
        float4 v = xr[k4];
        acc += v.x * w[(k4 * 4 + 0) * 16 + j];
        acc += v.y * w[(k4 * 4 + 1) * 16 + j];
        acc += v.z * w[(k4 * 4 + 2) * 16 + j];
        acc += v.w * w[(k4 * 4 + 3) * 16 + j];
    }
    float dv = dinv[n];
    t1[n * 16 + j] = acc;
    p1[n * 16 + j] = dv * dv * acc;
}

// ---- edge propagate (16-dim): pout[dst] += dinv[s]*dinv[d]*hin[src], 16 lanes/edge ----
__global__ __launch_bounds__(256) void k_edge(const int* __restrict__ src, const int* __restrict__ dst,
                                              const float* __restrict__ dinv,
                                              const float* __restrict__ hin, float* __restrict__ pout) {
    int gid = blockIdx.x * 256 + threadIdx.x;   // 25,600,000 exactly
    int e = gid >> 4, k = gid & 15;
    int s = src[e], d = dst[e];
    float norm = dinv[s] * dinv[d];
    float v = hin[s * 16 + k];
    atomicAdd(&pout[d * 16 + k], norm * v);
}

// ---- h1 = relu(p1 + b1); p2 = dinv^2 * h1 (self-loop init for layer 2) ----
__global__ __launch_bounds__(256) void k_relu1(const float* __restrict__ p1, const float* __restrict__ b1,
                                               const float* __restrict__ dinv,
                                               float* __restrict__ h1, float* __restrict__ p2) {
    int gid = blockIdx.x * 256 + threadIdx.x;   // 1,600,000 exactly
    int k = gid & 15, n = gid >> 4;
    float v = p1[gid] + b1[k];
    v = fmaxf(v, 0.f);
    h1[gid] = v;
    float dv = dinv[n];
    p2[gid] = dv * dv * v;
}

// ---- h2 = relu(p2 @ W2 + b2); sums[batch[n]] += h2 ----
__global__ __launch_bounds__(256) void k_h2pool(const float* __restrict__ p2, const float* __restrict__ W2,
                                               const float* __restrict__ b2, const int* __restrict__ batch,
                                               float* __restrict__ sums) {
    __shared__ float w[16 * 128];
    __shared__ float bb[128];
    __shared__ float pv[16][17];
    __shared__ int   bt[16];
    int t = threadIdx.x;
    {   // W2: 2048 floats
        const float4* wv = (const float4*)W2;
        ((float4*)w)[t * 2]     = wv[t * 2];
        ((float4*)w)[t * 2 + 1] = wv[t * 2 + 1];
    }
    if (t < 128) bb[t] = b2[t];
    int base = blockIdx.x * 16;                 // 6250 blocks
    if (t < 16) bt[t] = batch[base + t];
    pv[t >> 4][t & 15] = p2[base * 16 + t];
    __syncthreads();
    int j = t & 127, half = t >> 7;
    for (int i = 0; i < 8; ++i) {
        int nl = half * 8 + i;
        float acc = bb[j];
        #pragma unroll
        for (int k = 0; k < 16; ++k) acc += pv[nl][k] * w[k * 128 + j];
        acc = fmaxf(acc, 0.f);
        atomicAdd(&sums[bt[nl] * 128 + j], acc);
    }
}

// ---- z1 = relu(pooled @ LW1 + Lb1), 2 graphs per block ----
__global__ __launch_bounds__(256) void k_head1(const float* __restrict__ sums, const int* __restrict__ cntg,
                                               const float* __restrict__ LW1, const float* __restrict__ Lb1,
                                               float* __restrict__ z1) {
    __shared__ float srow[2][128];
    int t = threadIdx.x;
    int h = t >> 7, j = t & 127;
    int g = blockIdx.x * 2 + h;                 // 64 blocks
    float rc = 1.0f / fmaxf((float)cntg[g], 1.0f);
    srow[h][j] = sums[g * 128 + j] * rc;
    __syncthreads();
    float acc = Lb1[j];
    for (int k = 0; k < 128; ++k) acc += srow[h][k] * LW1[k * 128 + j];
    z1[g * 128 + j] = fmaxf(acc, 0.f);
}

// ---- z2 = z1 @ LW2 + Lb2; log_softmax over 2 classes; fp32 out ----
__global__ __launch_bounds__(256) void k_head2(const float* __restrict__ z1, const float* __restrict__ LW2,
                                               const float* __restrict__ Lb2, float* __restrict__ out) {
    int t = threadIdx.x;                        // 256 = 128 graphs x 2 classes
    int g = t >> 1, c = t & 1;
    float acc = Lb2[c];
    for (int j = 0; j < 128; ++j) acc += z1[g * 128 + j] * LW2[j * 2 + c];
    float other = __shfl_xor(acc, 1);
    float m = fmaxf(acc, other);
    float lse = m + logf(expf(acc - m) + expf(other - m));
    out[g * 2 + c] = acc - lse;
}

extern "C" void kernel_launch(void* const* d_in, const int* in_sizes, int n_in,
                              void* d_out, int out_size, void* d_ws, size_t ws_size,
                              hipStream_t stream) {
    const float* x   = (const float*)d_in[0];
    const int* ei    = (const int*)d_in[1];
    const int* batch = (const int*)d_in[2];
    const float* W1  = (const float*)d_in[3];
    const float* b1  = (const float*)d_in[4];
    const float* W2  = (const float*)d_in[5];
    const float* b2  = (const float*)d_in[6];
    const float* LW1 = (const float*)d_in[7];
    const float* Lb1 = (const float*)d_in[8];
    const float* LW2 = (const float*)d_in[9];
    const float* Lb2 = (const float*)d_in[10];
    const int* src = ei;
    const int* dst = ei + N_EDGES;

    char* ws = (char*)d_ws;
    int*   deg  = (int*)(ws);                 // 100000 ints   @ 0
    int*   cntg = (int*)(ws + 400000);        // 128 ints
    float* sums = (float*)(ws + 400512);      // 16384 f32
    float* dinv = (float*)(ws + 466048);      // 100000 f32
    float* A    = (float*)(ws + 866048);      // 1.6M f32 (t1, then p2)
    float* B    = (float*)(ws + 7266048);     // 1.6M f32 (p1, then h1)
    float* z1   = (float*)(ws + 13666048);    // 16384 f32
    float* out  = (float*)d_out;

    // zero atomic targets: deg, cntg, sums (contiguous prefix)
    hipMemsetAsync(ws, 0, 466048, stream);

    k_deg   <<<6250,   256, 0, stream>>>(dst, deg);
    k_cnt   <<<391,    256, 0, stream>>>(batch, cntg);
    k_dinv  <<<391,    256, 0, stream>>>(deg, dinv);
    k_gemm1 <<<6250,   256, 0, stream>>>(x, W1, dinv, A, B);      // t1=A, p1=B (+selfloop)
    k_edge  <<<100000, 256, 0, stream>>>(src, dst, dinv, A, B);   // p1 += edge msgs
    k_relu1 <<<6250,   256, 0, stream>>>(B, b1, dinv, B, A);      // h1=B, p2=A (+selfloop)
    k_edge  <<<100000, 256, 0, stream>>>(src, dst, dinv, B, A);   // p2 += edge msgs
    k_h2pool<<<6250,   256, 0, stream>>>(A, W2, b2, batch, sums);
    k_head1 <<<64,     256, 0, stream>>>(sums, cntg, LW1, Lb1, z1);
    k_head2 <<<1,      256, 0, stream>>>(z1, LW2, Lb2, out);
}